// Round 13
// baseline (206.169 us; speedup 1.0000x reference)
//
#include <hip/hip_runtime.h>
#include <hip/hip_bf16.h>

using bf16 = __hip_bfloat16;
typedef __attribute__((ext_vector_type(8))) short short8;
typedef __attribute__((ext_vector_type(4))) short s4v;
typedef __attribute__((ext_vector_type(4))) float float4v;
typedef __attribute__((ext_vector_type(4))) float f32x4;

#define MFMA16(a, b, c) __builtin_amdgcn_mfma_f32_16x16x32_bf16((a), (b), (c), 0, 0, 0)

// async global->LDS, 16B per lane, dest = wave-uniform base + lane*16
#define GLD_LDS16(g, l)                                            \
    __builtin_amdgcn_global_load_lds(                              \
        (const __attribute__((address_space(1))) void*)(g),        \
        (__attribute__((address_space(3))) void*)(l), 16, 0, 0)

constexpr int Bc = 2;
constexpr int Sc = 2048;
constexpr int Hc = 16;
constexpr int DKc = 64;
constexpr int Dc = 1024;
constexpr size_t MEG = 1024 * 1024;

union BFU { bf16 h; short s; };

__device__ inline short bfbits(float f) {
    BFU u; u.h = __float2bfloat16(f); return u.s;
}

__device__ inline short8 load_cvt8(const float* __restrict__ p) {
    f32x4 a = *(const f32x4*)p;
    f32x4 b = *(const f32x4*)(p + 4);
    short8 r;
    r[0] = bfbits(a[0]); r[1] = bfbits(a[1]); r[2] = bfbits(a[2]); r[3] = bfbits(a[3]);
    r[4] = bfbits(b[0]); r[5] = bfbits(b[1]); r[6] = bfbits(b[2]); r[7] = bfbits(b[3]);
    return r;
}

// ---------------------------------------------------------------------------
// One-shot fp32 -> bf16 conversion of x, Wq, Wk, Wv, Wo (8M elems) into ws.
// ---------------------------------------------------------------------------
__global__ __launch_bounds__(256) void cvt_kernel(
    const float* __restrict__ x, const float* __restrict__ Wq,
    const float* __restrict__ Wk, const float* __restrict__ Wv,
    const float* __restrict__ Wo, bf16* __restrict__ dst)
{
    const size_t i = ((size_t)blockIdx.x * 256 + threadIdx.x) * 8;
    const float* s;
    if      (i < 4 * MEG) s = x  + i;
    else if (i < 5 * MEG) s = Wq + (i - 4 * MEG);
    else if (i < 6 * MEG) s = Wk + (i - 5 * MEG);
    else if (i < 7 * MEG) s = Wv + (i - 6 * MEG);
    else                  s = Wo + (i - 7 * MEG);
    *(short8*)(dst + i) = load_cvt8(s);
}

// ---------------------------------------------------------------------------
// Fused QKV projection, async double-buffered staging (attn-style): ONE
// barrier per K-iter; prefetch of tile i+1 issued post-barrier, drained at
// the next barrier (a full compute phase later). grid (32 m, 24 sel*8+n):
// consecutive blocks share the W tile (L2). Q pre-scaled by (1/8)*log2e.
// ---------------------------------------------------------------------------
__global__ __launch_bounds__(256) void qkv_gemm_kernel(
    const bf16* __restrict__ x,
    const bf16* __restrict__ Wq, const float* __restrict__ bq,
    const bf16* __restrict__ Wk, const float* __restrict__ bk,
    const bf16* __restrict__ Wv, const float* __restrict__ bv,
    bf16* __restrict__ q_ws, bf16* __restrict__ k_ws, bf16* __restrict__ v_ws)
{
    constexpr int BM = 128, BN = 128, BK = 32, NIT = Dc / BK;
    __shared__ __align__(16) bf16 sA[2][BM * BK];   // 2 x 8 KB
    __shared__ __align__(16) bf16 sB[2][BN * BK];

    const int by = blockIdx.y;
    const int sel = by >> 3;               // 0=Q 1=K 2=V
    const int n0 = (by & 7) * BN;
    const int m0 = blockIdx.x * BM;

    const bf16* __restrict__ Wsel = (sel == 0) ? Wq : ((sel == 1) ? Wk : Wv);
    const float* __restrict__ bsel = (sel == 0) ? bq : ((sel == 1) ? bk : bv);

    const int t = threadIdx.x;
    const int lane = t & 63;
    const int wave = t >> 6;
    const int ln = lane & 15;
    const int qd = lane >> 4;
    const int wm = (wave >> 1) * 64;
    const int wn = (wave & 1) * 64;

    const int gr = lane >> 2;              // 0..15: row within 16-row chunk
    const int gc = (lane & 3) * 8;         // 0,8,16,24

    float4v acc[4][4];
#pragma unroll
    for (int i = 0; i < 4; i++)
#pragma unroll
        for (int j = 0; j < 4; j++) acc[i][j] = (float4v)0.0f;

    {   // stage tile 0 into buf 0
#pragma unroll
        for (int cc = 0; cc < 2; cc++) {
            const int c = wave * 2 + cc;
            GLD_LDS16(x    + (size_t)(m0 + c * 16 + gr) * Dc + gc, &sA[0][c * 512]);
            GLD_LDS16(Wsel + (size_t)(n0 + c * 16 + gr) * Dc + gc, &sB[0][c * 512]);
        }
    }

    for (int it = 0; it < NIT; it++) {
        const int cur = it & 1;
        __syncthreads();                   // drains prefetch; guards buf reuse
        if (it + 1 < NIT) {
            const int nxt = (it + 1) & 1;
            const int kk = (it + 1) * BK;
#pragma unroll
            for (int cc = 0; cc < 2; cc++) {
                const int c = wave * 2 + cc;
                GLD_LDS16(x    + (size_t)(m0 + c * 16 + gr) * Dc + kk + gc,
                          &sA[nxt][c * 512]);
                GLD_LDS16(Wsel + (size_t)(n0 + c * 16 + gr) * Dc + kk + gc,
                          &sB[nxt][c * 512]);
            }
        }

        short8 af[4], wf[4];
#pragma unroll
        for (int i = 0; i < 4; i++)
            af[i] = *(const short8*)&sA[cur][(wm + i * 16 + ln) * BK + qd * 8];
#pragma unroll
        for (int j = 0; j < 4; j++)
            wf[j] = *(const short8*)&sB[cur][(wn + j * 16 + ln) * BK + qd * 8];
#pragma unroll
        for (int i = 0; i < 4; i++)
#pragma unroll
            for (int j = 0; j < 4; j++)
                acc[i][j] = MFMA16(af[i], wf[j], acc[i][j]);
    }

    constexpr float QSCALE = 0.125f * 1.44269504088896f;

#pragma unroll
    for (int j = 0; j < 4; j++) {
        const int n = n0 + wn + j * 16 + ln;
        const float bias = bsel[n];
        const int h_ = n >> 6, d_ = n & 63;
#pragma unroll
        for (int i = 0; i < 4; i++) {
            const int mbase = m0 + wm + i * 16 + qd * 4;
            if (sel == 2) {                // V^T: 4 s-contiguous -> one 8B store
                const int b_ = mbase >> 11, s_ = mbase & 2047;
                s4v pk;
#pragma unroll
                for (int r = 0; r < 4; r++)
                    pk[r] = bfbits(acc[i][j][r] + bias);
                *(s4v*)&v_ws[(((size_t)(b_ * Hc + h_)) * DKc + d_) * Sc + s_] = pk;
            } else {
#pragma unroll
                for (int r = 0; r < 4; r++) {
                    const int m = mbase + r;
                    const int b_ = m >> 11, s_ = m & 2047;
                    float v = acc[i][j][r] + bias;
                    if (sel == 0) v *= QSCALE;
                    const bf16 o = __float2bfloat16(v);
                    if (sel == 0)
                        q_ws[(((size_t)(b_ * Hc + h_)) * Sc + s_) * DKc + d_] = o;
                    else
                        k_ws[(((size_t)(b_ * Hc + h_)) * Sc + s_) * DKc + d_] = o;
                }
            }
        }
    }
}

// ---------------------------------------------------------------------------
// Flash attention v4 (round-12, validated): 512 threads (8 waves x 16 q-rows),
// 128-row Q-tile, async dbuf K/V (xor swizzle, 0 conflicts), ONE barrier per
// ktile, swapped-operand QK^T, ones-column denominator. grid (32 bh, 16 qt).
// ---------------------------------------------------------------------------
__global__ __launch_bounds__(512) void attn_kernel(
    const bf16* __restrict__ q_ws, const bf16* __restrict__ k_ws,
    const bf16* __restrict__ v_ws, bf16* __restrict__ ao_ws)
{
    constexpr int LQP = 76;  // short row stride for sP
    __shared__ __align__(16) bf16 sQ[128 * 64];      // swizzled, staged once
    __shared__ __align__(16) bf16 sK[2][64 * 64];    // swizzled dbuf
    __shared__ __align__(16) bf16 sV[2][64 * 64];    // V^T [d][key], swizzled dbuf
    __shared__ __align__(16) short sP[8][16 * LQP];  // per-wave P [qrow][key]

    const int bh = blockIdx.x;
    const int qt = blockIdx.y;
    const int t = threadIdx.x;
    const int lane = t & 63;
    const int wave = t >> 6;               // 0..7
    const int ln = lane & 15;
    const int qd = lane >> 4;
    short* const sPw = sP[wave];

    const bf16* __restrict__ Qbase = q_ws + (size_t)bh * Sc * DKc + qt * 128 * DKc;
    const bf16* __restrict__ Kbase = k_ws + (size_t)bh * Sc * DKc;
    const bf16* __restrict__ Vbase = v_ws + (size_t)bh * DKc * Sc;

    const int rloc = lane >> 3;            // 0..7 row within 8-row chunk
    const int blk = lane & 7;              // LDS 16B-block index

    {   // stage Q (128x64) async, swizzled: LDS[r][b] = G[r][b^(r&7)]
#pragma unroll
        for (int cc = 0; cc < 2; cc++) {
            const int c = wave * 2 + cc;
            const int row = c * 8 + rloc;
            const int gb = blk ^ (row & 7);
            GLD_LDS16(Qbase + (size_t)row * DKc + gb * 8, &sQ[c * 512]);
        }
    }
    {   // stage K/V tile 0 async
        const int row = wave * 8 + rloc;
        const int gb = blk ^ (row & 7);
        GLD_LDS16(Kbase + (size_t)row * DKc + gb * 8, &sK[0][wave * 512]);
        GLD_LDS16(Vbase + (size_t)row * Sc + gb * 8, &sV[0][wave * 512]);
    }

    // constant ones B-frag: B[n=64+ln][k]=1 iff ln==0 (denominator column)
    short8 ones8;
    {
        const short ob = (ln == 0) ? (short)0x3F80 : (short)0;
#pragma unroll
        for (int i = 0; i < 8; i++) ones8[i] = ob;
    }

    float4v oacc[5];
#pragma unroll
    for (int j = 0; j < 5; j++) oacc[j] = (float4v)0.0f;

    for (int kt = 0; kt < Sc / 64; kt++) {
        const int cur = kt & 1;
        __syncthreads();
        if (kt + 1 < Sc / 64) {
            const int nxt = (kt + 1) & 1;
            const int row = wave * 8 + rloc;
            const int gb = blk ^ (row & 7);
            GLD_LDS16(Kbase + (size_t)((kt + 1) * 64 + row) * DKc + gb * 8,
                      &sK[nxt][wave * 512]);
            GLD_LDS16(Vbase + (size_t)row * Sc + (kt + 1) * 64 + gb * 8,
                      &sV[nxt][wave * 512]);
        }

        // S^T = K Q^T: A=K[m=key], B=Q[n=qrow]; C col=qrow(ln), row=key(qd*4+r)
        float4v sacc[4];
#pragma unroll
        for (int j = 0; j < 4; j++) sacc[j] = (float4v)0.0f;
#pragma unroll
        for (int ks = 0; ks < 2; ks++) {
            const int qrow = wave * 16 + ln;
            const short8 bq = *(const short8*)
                &sQ[qrow * 64 + (((ks * 4 + qd) ^ (qrow & 7)) << 3)];
#pragma unroll
            for (int j = 0; j < 4; j++) {
                const int row = j * 16 + ln;
                const short8 ak = *(const short8*)
                    &sK[cur][row * 64 + (((ks * 4 + qd) ^ (row & 7)) << 3)];
                sacc[j] = MFMA16(ak, bq, sacc[j]);
            }
        }

        // P = exp2(S^T) -> sP [qrow][key]: lane holds qrow=ln, keys 4-contig.
#pragma unroll
        for (int j = 0; j < 4; j++) {
            s4v pk;
#pragma unroll
            for (int r = 0; r < 4; r++)
                pk[r] = bfbits(exp2f(sacc[j][r]));
            *(s4v*)&sPw[ln * LQP + j * 16 + qd * 4] = pk;
        }

        // O += P V: A=P[m=qrow], B=V^T[n=d]; ones-frag accumulates denominator.
#pragma unroll
        for (int ks = 0; ks < 2; ks++) {
            const s4v p0 = *(const s4v*)&sPw[ln * LQP + ks * 32 + qd * 8];
            const s4v p1 = *(const s4v*)&sPw[ln * LQP + ks * 32 + qd * 8 + 4];
            short8 ap;
            ap[0] = p0[0]; ap[1] = p0[1]; ap[2] = p0[2]; ap[3] = p0[3];
            ap[4] = p1[0]; ap[5] = p1[1]; ap[6] = p1[2]; ap[7] = p1[3];
#pragma unroll
            for (int j = 0; j < 4; j++) {
                const int row = j * 16 + ln;
                const short8 bv_ = *(const short8*)
                    &sV[cur][row * 64 + (((ks * 4 + qd) ^ (row & 7)) << 3)];
                oacc[j] = MFMA16(ap, bv_, oacc[j]);
            }
            oacc[4] = MFMA16(ap, ones8, oacc[4]);
        }
    }

    // denominator = col n=64 => lane (qd*16); broadcast within quad.
    const int b_ = bh >> 4, h_ = bh & 15;
#pragma unroll
    for (int r = 0; r < 4; r++) {
        const float l = __shfl(oacc[4][r], lane & 48, 64);
        const float inv = 1.0f / l;
        const int s_ = qt * 128 + wave * 16 + qd * 4 + r;
#pragma unroll
        for (int j = 0; j < 4; j++) {
            const int d_ = j * 16 + ln;
            ao_ws[(((size_t)(b_ * Sc + s_)) * Hc + h_) * DKc + d_] =
                __float2bfloat16(oacc[j][r] * inv);
        }
    }
}

// ---------------------------------------------------------------------------
// Output projection, async double-buffered (1 barrier/iter): out = ao.Wo^T+bo.
// grid (32 m, 8 n): consecutive blocks share the W tile.
// ---------------------------------------------------------------------------
__global__ __launch_bounds__(256) void out_gemm_kernel(
    const bf16* __restrict__ A, const bf16* __restrict__ Wo,
    const float* __restrict__ bo, float* __restrict__ out)
{
    constexpr int BM = 128, BN = 128, BK = 32, NIT = Dc / BK;
    __shared__ __align__(16) bf16 sA[2][BM * BK];
    __shared__ __align__(16) bf16 sB[2][BN * BK];

    const int m0 = blockIdx.x * BM;
    const int n0 = blockIdx.y * BN;

    const int t = threadIdx.x;
    const int lane = t & 63;
    const int wave = t >> 6;
    const int ln = lane & 15;
    const int qd = lane >> 4;
    const int wm = (wave >> 1) * 64;
    const int wn = (wave & 1) * 64;

    const int gr = lane >> 2;
    const int gc = (lane & 3) * 8;

    float4v acc[4][4];
#pragma unroll
    for (int i = 0; i < 4; i++)
#pragma unroll
        for (int j = 0; j < 4; j++) acc[i][j] = (float4v)0.0f;

    {
#pragma unroll
        for (int cc = 0; cc < 2; cc++) {
            const int c = wave * 2 + cc;
            GLD_LDS16(A  + (size_t)(m0 + c * 16 + gr) * Dc + gc, &sA[0][c * 512]);
            GLD_LDS16(Wo + (size_t)(n0 + c * 16 + gr) * Dc + gc, &sB[0][c * 512]);
        }
    }

    for (int it = 0; it < NIT; it++) {
        const int cur = it & 1;
        __syncthreads();
        if (it + 1 < NIT) {
            const int nxt = (it + 1) & 1;
            const int kk = (it + 1) * BK;
#pragma unroll
            for (int cc = 0; cc < 2; cc++) {
                const int c = wave * 2 + cc;
                GLD_LDS16(A  + (size_t)(m0 + c * 16 + gr) * Dc + kk + gc,
                          &sA[nxt][c * 512]);
                GLD_LDS16(Wo + (size_t)(n0 + c * 16 + gr) * Dc + kk + gc,
                          &sB[nxt][c * 512]);
            }
        }

        short8 af[4], wf[4];
#pragma unroll
        for (int i = 0; i < 4; i++)
            af[i] = *(const short8*)&sA[cur][(wm + i * 16 + ln) * BK + qd * 8];
#pragma unroll
        for (int j = 0; j < 4; j++)
            wf[j] = *(const short8*)&sB[cur][(wn + j * 16 + ln) * BK + qd * 8];
#pragma unroll
        for (int i = 0; i < 4; i++)
#pragma unroll
            for (int j = 0; j < 4; j++)
                acc[i][j] = MFMA16(af[i], wf[j], acc[i][j]);
    }

#pragma unroll
    for (int j = 0; j < 4; j++) {
        const int n = n0 + wn + j * 16 + ln;
        const float bias = bo[n];
#pragma unroll
        for (int i = 0; i < 4; i++) {
            const int mbase = m0 + wm + i * 16 + qd * 4;
#pragma unroll
            for (int r = 0; r < 4; r++) {
                const int m = mbase + r;
                out[(size_t)m * Dc + n] = acc[i][j][r] + bias;
            }
        }
    }
}

// ---------------------------------------------------------------------------
extern "C" void kernel_launch(void* const* d_in, const int* in_sizes, int n_in,
                              void* d_out, int out_size, void* d_ws, size_t ws_size,
                              hipStream_t stream)
{
    const float* x  = (const float*)d_in[0];
    const float* Wq = (const float*)d_in[1];
    const float* bq = (const float*)d_in[2];
    const float* Wk = (const float*)d_in[3];
    const float* bk = (const float*)d_in[4];
    const float* Wv = (const float*)d_in[5];
    const float* bv = (const float*)d_in[6];
    const float* Wo = (const float*)d_in[7];
    const float* bo = (const float*)d_in[8];
    float* out = (float*)d_out;

    bf16* base  = (bf16*)d_ws;
    bf16* q_ws  = base;                      // (b,h,s,d), pre-scaled
    bf16* k_ws  = base + 4 * MEG;            // (b,h,s,d)
    bf16* v_ws  = base + 8 * MEG;            // (b,h,d,s)  transposed
    bf16* ao_ws = base + 12 * MEG;           // (b,s,h,d) == (4096,1024)
    bf16* xb    = base + 16 * MEG;           // bf16 copies of inputs
    bf16* wqb   = base + 20 * MEG;
    bf16* wkb   = base + 21 * MEG;
    bf16* wvb   = base + 22 * MEG;
    bf16* wob   = base + 23 * MEG;

    cvt_kernel<<<dim3(4096), 256, 0, stream>>>(x, Wq, Wk, Wv, Wo, xb);
    qkv_gemm_kernel<<<dim3(32, 24), 256, 0, stream>>>(
        xb, wqb, bq, wkb, bk, wvb, bv, q_ws, k_ws, v_ws);
    attn_kernel<<<dim3(32, 16), 512, 0, stream>>>(q_ws, k_ws, v_ws, ao_ws);
    out_gemm_kernel<<<dim3(32, 8), 256, 0, stream>>>(ao_ws, wob, bo, out);
}